// Round 5
// baseline (170.324 us; speedup 1.0000x reference)
//
#include <hip/hip_runtime.h>

#define CAP 80  // bucket capacity per node; in-degree Poisson(16), max ~45 over 50K nodes

typedef __attribute__((ext_vector_type(8))) short short8;  // 8 bf16 MFMA A/B frag
typedef __attribute__((ext_vector_type(4))) float f32x4;   // 4 fp32 (MFMA C/D frag, NT I/O)
typedef __attribute__((ext_vector_type(4))) unsigned int u32x4;  // 16B int vector (NT I/O)

static inline size_t alignup(size_t x) { return (x + 255) & ~(size_t)255; }

__device__ __forceinline__ unsigned short f2bf(float f) {  // RNE fp32->bf16
    unsigned int u = __float_as_uint(f);
    u = (u + 0x7fffu + ((u >> 16) & 1u)) >> 16;
    return (unsigned short)u;
}

// ---------- prep: zero cnt; Wt[n][k] = bf16(W[k][n]) (B^T for MFMA) ----------
__global__ __launch_bounds__(256) void k_prep(const float* __restrict__ W1,
                                              const float* __restrict__ W2,
                                              unsigned short* __restrict__ Wt1,
                                              unsigned short* __restrict__ Wt2,
                                              int* __restrict__ cnt, int n) {
    int i = blockIdx.x * 256 + threadIdx.x;
    if (i < n) cnt[i] = 0;
    if (i < 128 * 128) { int k = i >> 7, c = i & 127; Wt1[(size_t)c * 128 + k] = f2bf(W1[i]); }
    if (i < 128 * 64)  { int k = i >> 6, c = i & 63;  Wt2[(size_t)c * 128 + k] = f2bf(W2[i]); }
}

// ---------- MFMA GEMM body (LDS-free): out[m,:] = bf16( relu?(A[m,:]+bias) @ W ) ----------
// K=128 fixed. A direct-from-global (NT: single-use). Wt cached (reused).
// m97-verified operands: A rows k-contig, Wt rows k-contig; C: col=lane&15, row=(lane>>4)*4+reg.
template <int NT, bool IN_BF16, bool BIAS_RELU>
__device__ __forceinline__ void gemm_body(int bid, const void* __restrict__ Ap,
                                          const unsigned short* __restrict__ Wt,
                                          const float* __restrict__ bias,
                                          unsigned short* __restrict__ out, int M) {
    const int lane = threadIdx.x & 63;
    const int wave = threadIdx.x >> 6;
    const int m0 = bid * 64 + wave * 16;
    const int lrow = lane & 15;
    const int lk = lane >> 4;
    int arow = m0 + lrow;
    if (arow >= M) arow = M - 1;  // clamp; garbage rows never stored

    f32x4 acc[NT];
#pragma unroll
    for (int t = 0; t < NT; ++t) acc[t] = (f32x4){0.f, 0.f, 0.f, 0.f};

#pragma unroll
    for (int k0 = 0; k0 < 4; ++k0) {
        const int kb = k0 * 32 + lk * 8;
        short8 afrag;
        if (IN_BF16) {
            const unsigned short* A = (const unsigned short*)Ap;
            u32x4 v = __builtin_nontemporal_load((const u32x4*)&A[(size_t)arow * 128 + kb]);
#pragma unroll
            for (int q = 0; q < 4; ++q) {
                float lo = __uint_as_float(v[q] << 16);
                float hi = __uint_as_float(v[q] & 0xffff0000u);
                if (BIAS_RELU) {
                    lo = fmaxf(lo + bias[kb + 2 * q], 0.f);
                    hi = fmaxf(hi + bias[kb + 2 * q + 1], 0.f);
                }
                afrag[2 * q] = (short)f2bf(lo);
                afrag[2 * q + 1] = (short)f2bf(hi);
            }
        } else {
            const float* A = (const float*)Ap;
            const float* ap = &A[(size_t)arow * 128 + kb];
            f32x4 v0 = __builtin_nontemporal_load((const f32x4*)ap);
            f32x4 v1 = __builtin_nontemporal_load((const f32x4*)(ap + 4));
#pragma unroll
            for (int q = 0; q < 4; ++q) {
                afrag[q] = (short)f2bf(v0[q]);
                afrag[4 + q] = (short)f2bf(v1[q]);
            }
        }
#pragma unroll
        for (int t = 0; t < NT; ++t) {
            const int bcol = t * 16 + lrow;
            short8 bfrag = *(const short8*)&Wt[(size_t)bcol * 128 + kb];
            acc[t] = __builtin_amdgcn_mfma_f32_16x16x32_bf16(afrag, bfrag, acc[t], 0, 0, 0);
        }
    }

#pragma unroll
    for (int i = 0; i < 4; ++i) {
        int row = m0 + lk * 4 + i;
        if (row < M) {
#pragma unroll
            for (int t = 0; t < NT; ++t)
                out[(size_t)row * (NT * 16) + t * 16 + lrow] = f2bf(acc[t][i]);
        }
    }
}

// ---------- XCD-local bucketed-CSR fill body ----------
// Group g = f&7 (blockIdx round-robin ~ XCD). Group g owns dest range
// [g*span,(g+1)*span): its cnt lines + bucket rows stay in ONE XCD's L2
// (local atomics, merged sector writes). Coverage exact regardless of mapping.
__device__ __forceinline__ void fill_body(int f, int FB,
                                          const int* __restrict__ colp,
                                          const int* __restrict__ rowp,
                                          int* __restrict__ cnt,
                                          int* __restrict__ bucket, int nE, int n) {
    const int g = f & 7;
    const int r = f >> 3;
    const int NPG = FB >> 3;
    const int span = (n + 7) >> 3;
    const int lo = g * span;
    const int hi = (lo + span < n) ? lo + span : n;
    for (int e = r * 256 + (int)threadIdx.x; e < nE; e += NPG * 256) {
        int c = __builtin_nontemporal_load(&colp[e]);
        if (c >= lo && c < hi) {
            int rw = __builtin_nontemporal_load(&rowp[e]);
            int slot = atomicAdd(&cnt[c], 1);
            if (slot < CAP) bucket[(size_t)c * CAP + slot] = rw;
        }
    }
}

// ---------- fused: fill (blocks 0..FB-1) || gemm1 (blocks FB..FB+G1-1) ----------
__global__ __launch_bounds__(256) void k_fused(const int* __restrict__ colp,
                                               const int* __restrict__ rowp,
                                               int* __restrict__ cnt,
                                               int* __restrict__ bucket, int nE, int n,
                                               const float* __restrict__ x,
                                               const unsigned short* __restrict__ Wt1,
                                               unsigned short* __restrict__ hs1, int FB) {
    int b = blockIdx.x;
    if (b < FB)
        fill_body(b, FB, colp, rowp, cnt, bucket, nE, n);
    else
        gemm_body<8, false, false>(b - FB, x, Wt1, nullptr, hs1, n);
}

__global__ __launch_bounds__(256) void k_gemm2(const unsigned short* __restrict__ agg1,
                                               const unsigned short* __restrict__ Wt2,
                                               const float* __restrict__ b1,
                                               unsigned short* __restrict__ hs2, int M) {
    gemm_body<4, true, true>(blockIdx.x, agg1, Wt2, b1, hs2, M);
}

__device__ __forceinline__ void acc8s(float a[8], u32x4 u, float d) {
    a[0] = fmaf(__uint_as_float(u[0] << 16), d, a[0]);
    a[1] = fmaf(__uint_as_float(u[0] & 0xffff0000u), d, a[1]);
    a[2] = fmaf(__uint_as_float(u[1] << 16), d, a[2]);
    a[3] = fmaf(__uint_as_float(u[1] & 0xffff0000u), d, a[3]);
    a[4] = fmaf(__uint_as_float(u[2] << 16), d, a[4]);
    a[5] = fmaf(__uint_as_float(u[2] & 0xffff0000u), d, a[5]);
    a[6] = fmaf(__uint_as_float(u[3] << 16), d, a[6]);
    a[7] = fmaf(__uint_as_float(u[3] & 0xffff0000u), d, a[7]);
}

// ---------- gather: res[v,:] = dis[v]*( dis[v]*hs[v,:] + sum_r dis[r]*hs[r,:] ) (+bias)
// dis computed on the fly from cnt (L2-resident). hs cached; bucket NT; out NT-stored.
template <int D, bool OUT_F32, bool ADD_BIAS>
__global__ __launch_bounds__(256) void k_gather_bf(const unsigned short* __restrict__ hs,
                                                   const int* __restrict__ bucket,
                                                   const int* __restrict__ cnt,
                                                   const float* __restrict__ bias,
                                                   void* __restrict__ outp, int n) {
    const int TPN = D / 8;
    const int NPB = 256 / TPN;
    int v = blockIdx.x * NPB + (int)(threadIdx.x / TPN);
    int c = threadIdx.x % TPN;
    if (v >= n) return;
    const u32x4* h4 = (const u32x4*)hs;
    const size_t rs = D / 8;
    size_t base = (size_t)v * rs + c;

    int dt = cnt[v];
    float dv = rsqrtf((float)(dt + 1));
    int deg = dt > CAP ? CAP : dt;

    float a[8];
#pragma unroll
    for (int j = 0; j < 8; ++j) a[j] = 0.f;
    acc8s(a, h4[base], dv);  // self-loop term, weight dis[v]

    const int* bk = bucket + (size_t)v * CAP;
    int s = 0;
    for (; s + 4 <= deg; s += 4) {
        int r0 = __builtin_nontemporal_load(&bk[s]);
        int r1 = __builtin_nontemporal_load(&bk[s + 1]);
        int r2 = __builtin_nontemporal_load(&bk[s + 2]);
        int r3 = __builtin_nontemporal_load(&bk[s + 3]);
        float d0 = rsqrtf((float)(cnt[r0] + 1));
        float d1 = rsqrtf((float)(cnt[r1] + 1));
        float d2 = rsqrtf((float)(cnt[r2] + 1));
        float d3 = rsqrtf((float)(cnt[r3] + 1));
        u32x4 m0 = h4[(size_t)r0 * rs + c];
        u32x4 m1 = h4[(size_t)r1 * rs + c];
        u32x4 m2 = h4[(size_t)r2 * rs + c];
        u32x4 m3 = h4[(size_t)r3 * rs + c];
        acc8s(a, m0, d0); acc8s(a, m1, d1); acc8s(a, m2, d2); acc8s(a, m3, d3);
    }
    for (; s < deg; ++s) {
        int r = __builtin_nontemporal_load(&bk[s]);
        float d = rsqrtf((float)(cnt[r] + 1));
        acc8s(a, h4[(size_t)r * rs + c], d);
    }

    if (OUT_F32) {
        float* o = (float*)outp;
        float rr[8];
#pragma unroll
        for (int j = 0; j < 8; ++j) {
            rr[j] = a[j] * dv;
            if (ADD_BIAS) rr[j] += bias[c * 8 + j];
        }
        f32x4 lov = {rr[0], rr[1], rr[2], rr[3]};
        f32x4 hiv = {rr[4], rr[5], rr[6], rr[7]};
        __builtin_nontemporal_store(lov, (f32x4*)&o[(size_t)v * D + c * 8]);
        __builtin_nontemporal_store(hiv, (f32x4*)&o[(size_t)v * D + c * 8 + 4]);
    } else {
        u32x4 o;
        o[0] = (unsigned)f2bf(a[0] * dv) | ((unsigned)f2bf(a[1] * dv) << 16);
        o[1] = (unsigned)f2bf(a[2] * dv) | ((unsigned)f2bf(a[3] * dv) << 16);
        o[2] = (unsigned)f2bf(a[4] * dv) | ((unsigned)f2bf(a[5] * dv) << 16);
        o[3] = (unsigned)f2bf(a[6] * dv) | ((unsigned)f2bf(a[7] * dv) << 16);
        __builtin_nontemporal_store(o, (u32x4*)outp + base);
    }
}

extern "C" void kernel_launch(void* const* d_in, const int* in_sizes, int n_in,
                              void* d_out, int out_size, void* d_ws, size_t ws_size,
                              hipStream_t stream) {
    const float* x  = (const float*)d_in[0];
    const int*   ei = (const int*)d_in[1];
    const float* W1 = (const float*)d_in[2];
    const float* b1 = (const float*)d_in[3];
    const float* W2 = (const float*)d_in[4];
    const float* b2 = (const float*)d_in[5];

    const int Din = 128;
    const int Nn = in_sizes[0] / Din;   // 50000
    const int E  = in_sizes[1] / 2;     // 800000
    const int* rowp = ei;
    const int* colp = ei + E;

    char* ws = (char*)d_ws;
    size_t off = 0;
    int*            cnt    = (int*)(ws + off);            off = alignup(off + (size_t)Nn * 4);
    int*            bucket = (int*)(ws + off);            off = alignup(off + (size_t)Nn * CAP * 4);
    unsigned short* Wt1    = (unsigned short*)(ws + off); off = alignup(off + 128 * 128 * 2);
    unsigned short* Wt2    = (unsigned short*)(ws + off); off = alignup(off + 128 * 64 * 2);
    unsigned short* hs1    = (unsigned short*)(ws + off); off = alignup(off + (size_t)Nn * 128 * 2);
    unsigned short* agg1   = (unsigned short*)(ws + off); off = alignup(off + (size_t)Nn * 128 * 2);
    unsigned short* hs2    = hs1;  // hs1 dead after gather1; reuse (64 <= 128 cols)
    float*          outp   = (float*)d_out;

    // prep: zero cnt + bf16-transpose both weights
    k_prep<<<(Nn + 255) / 256, 256, 0, stream>>>(W1, W2, Wt1, Wt2, cnt, Nn);

    // fused: XCD-local CSR fill (512 blocks, 8 groups) || gemm1 hs1 = bf16(x @ W1)
    const int FB = 512;
    const int G1 = (Nn + 63) / 64;
    k_fused<<<FB + G1, 256, 0, stream>>>(colp, rowp, cnt, bucket, E, Nn, x, Wt1, hs1, FB);

    // agg1 = bf16( dis[v] * (dis[v]*hs1[v] + sum_r dis[r]*hs1[r]) )
    k_gather_bf<128, false, false><<<(Nn + 15) / 16, 256, 0, stream>>>(
        hs1, bucket, cnt, nullptr, agg1, Nn);

    // hs2 = bf16( relu(agg1 + b1) @ W2 )
    k_gemm2<<<(Nn + 63) / 64, 256, 0, stream>>>(agg1, Wt2, b1, hs2, Nn);

    // out = dis[v] * (dis[v]*hs2[v] + sum_r dis[r]*hs2[r]) + b2   (fp32)
    k_gather_bf<64, true, true><<<(Nn + 31) / 32, 256, 0, stream>>>(
        hs2, bucket, cnt, b2, (void*)outp, Nn);
}

// Round 6
// 119.514 us; speedup vs baseline: 1.4251x; 1.4251x over previous
//
#include <hip/hip_runtime.h>

#define NB 196      // bins of 256 nodes: ceil(50000/256)
#define BSH 8       // bin shift
#define BMSK 255
#define NBLK_A 512  // phase-A blocks
#define BINCAP 6144 // max edges per bin (avg 4096, sigma 64 -> +32 sigma)

typedef __attribute__((ext_vector_type(8))) short short8;
typedef __attribute__((ext_vector_type(4))) float f32x4;
typedef __attribute__((ext_vector_type(4))) unsigned int u32x4;

static inline size_t alignup(size_t x) { return (x + 255) & ~(size_t)255; }

__device__ __forceinline__ unsigned short f2bf(float f) {  // RNE fp32->bf16
    unsigned int u = __float_as_uint(f);
    u = (u + 0x7fffu + ((u >> 16) & 1u)) >> 16;
    return (unsigned short)u;
}

// ---- phase A1: per-block bin histogram (blocks 0..511) + weight transpose (blocks 512+)
__global__ __launch_bounds__(256) void k_hist(const int* __restrict__ colp, int nE,
                                              unsigned* __restrict__ counts,
                                              const float* __restrict__ W1,
                                              const float* __restrict__ W2,
                                              unsigned short* __restrict__ Wt1,
                                              unsigned short* __restrict__ Wt2) {
    int blk = blockIdx.x;
    if (blk >= NBLK_A) {  // weight prep: Wt[n][k] = bf16(W[k][n])
        int i = (blk - NBLK_A) * 256 + threadIdx.x;
        if (i < 128 * 128) { int k = i >> 7, c = i & 127; Wt1[(size_t)c * 128 + k] = f2bf(W1[i]); }
        if (i < 128 * 64)  { int k = i >> 6, c = i & 63;  Wt2[(size_t)c * 128 + k] = f2bf(W2[i]); }
        return;
    }
    __shared__ unsigned h[NB];
    for (int i = threadIdx.x; i < NB; i += 256) h[i] = 0;
    __syncthreads();
    int chunk = (nE + NBLK_A - 1) / NBLK_A;
    int e0 = blk * chunk, e1 = min(nE, e0 + chunk);
    for (int e = e0 + (int)threadIdx.x; e < e1; e += 256)
        atomicAdd(&h[colp[e] >> BSH], 1u);
    __syncthreads();
    for (int i = threadIdx.x; i < NB; i += 256) counts[(size_t)i * NBLK_A + blk] = h[i];
}

// ---- phase A2a: exclusive scan of each bin's 512 per-block counts; bintot
__global__ __launch_bounds__(256) void k_scanA(unsigned* __restrict__ counts,
                                               unsigned* __restrict__ bintot) {
    int bin = blockIdx.x, t = threadIdx.x;
    __shared__ unsigned ps[256];
    unsigned c0 = counts[(size_t)bin * NBLK_A + 2 * t];
    unsigned c1 = counts[(size_t)bin * NBLK_A + 2 * t + 1];
    unsigned s = c0 + c1;
    ps[t] = s;
    __syncthreads();
    for (int d = 1; d < 256; d <<= 1) {
        unsigned v = (t >= d) ? ps[t - d] : 0u;
        __syncthreads();
        ps[t] += v;
        __syncthreads();
    }
    unsigned base = ps[t] - s;  // exclusive
    counts[(size_t)bin * NBLK_A + 2 * t] = base;
    counts[(size_t)bin * NBLK_A + 2 * t + 1] = base + c0;
    if (t == 255) bintot[bin] = ps[255];
}

// ---- phase A2b: bin bases (edgebase[NB] = nE)
__global__ __launch_bounds__(256) void k_scanB(const unsigned* __restrict__ bintot,
                                               unsigned* __restrict__ edgebase, int nE) {
    __shared__ unsigned bt[NB];
    int t = threadIdx.x;
    if (t < NB) bt[t] = bintot[t];
    __syncthreads();
    if (t == 0) {
        unsigned run = 0;
        for (int b = 0; b < NB; ++b) { unsigned v = bt[b]; bt[b] = run; run += v; }
    }
    __syncthreads();
    if (t < NB) edgebase[t] = bt[t];
    if (t == 0) edgebase[NB] = (unsigned)nE;
}

// ---- phase A3: scatter packed (row<<8 | col_low) into bin segments (dense runs)
__global__ __launch_bounds__(256) void k_scatter(const int* __restrict__ colp,
                                                 const int* __restrict__ rowp, int nE,
                                                 const unsigned* __restrict__ counts,
                                                 const unsigned* __restrict__ edgebase,
                                                 unsigned* __restrict__ pairs) {
    __shared__ unsigned cur[NB];
    int blk = blockIdx.x;
    for (int i = threadIdx.x; i < NB; i += 256)
        cur[i] = edgebase[i] + counts[(size_t)i * NBLK_A + blk];
    __syncthreads();
    int chunk = (nE + NBLK_A - 1) / NBLK_A;
    int e0 = blk * chunk, e1 = min(nE, e0 + chunk);
    for (int e = e0 + (int)threadIdx.x; e < e1; e += 256) {
        int c = colp[e], r = rowp[e];
        unsigned pos = atomicAdd(&cur[c >> BSH], 1u);
        pairs[pos] = ((unsigned)r << BSH) | (unsigned)(c & BMSK);
    }
}

// ---- phase B: per-bin CSR build in LDS; write csr + off + dis (all dense)
__global__ __launch_bounds__(256) void k_binbuild(const unsigned* __restrict__ pairs,
                                                  const unsigned* __restrict__ edgebase,
                                                  unsigned* __restrict__ csr,
                                                  unsigned* __restrict__ off,
                                                  float* __restrict__ dis, int n) {
    __shared__ unsigned lp[BINCAP];
    __shared__ unsigned lr[BINCAP];
    __shared__ unsigned hist[256];
    __shared__ unsigned scn[256];
    int b = blockIdx.x, t = threadIdx.x;
    unsigned e0 = edgebase[b], e1 = edgebase[b + 1];
    unsigned ec = e1 - e0;
    if (ec > BINCAP) ec = BINCAP;
    hist[t] = 0;
    __syncthreads();
    for (unsigned i = t; i < ec; i += 256) {
        unsigned v = pairs[e0 + i];
        lp[i] = v;
        atomicAdd(&hist[v & BMSK], 1u);
    }
    __syncthreads();
    unsigned hv = hist[t];
    scn[t] = hv;
    __syncthreads();
    for (int d = 1; d < 256; d <<= 1) {
        unsigned v = (t >= d) ? scn[t - d] : 0u;
        __syncthreads();
        scn[t] += v;
        __syncthreads();
    }
    unsigned ex = scn[t] - hv;  // exclusive
    int node = (b << BSH) + t;
    if (node < n) {
        off[node] = e0 + ex;
        dis[node] = rsqrtf((float)(hv + 1));
    }
    if (b == NB - 1 && t == 0) off[n] = e1;  // sentinel = nE
    __syncthreads();
    scn[t] = ex;  // repurpose as cursor
    __syncthreads();
    for (unsigned i = t; i < ec; i += 256) {
        unsigned v = lp[i];
        unsigned pos = atomicAdd(&scn[v & BMSK], 1u);
        lr[pos] = v >> BSH;
    }
    __syncthreads();
    for (unsigned i = t; i < ec; i += 256) csr[e0 + i] = lr[i];
}

// ---------- MFMA GEMM body (LDS-free): out[m,:] = bf16( relu?(A[m,:]+bias) @ W ) ----------
template <int NT, bool IN_BF16, bool BIAS_RELU>
__device__ __forceinline__ void gemm_body(int bid, const void* __restrict__ Ap,
                                          const unsigned short* __restrict__ Wt,
                                          const float* __restrict__ bias,
                                          unsigned short* __restrict__ out, int M) {
    const int lane = threadIdx.x & 63;
    const int wave = threadIdx.x >> 6;
    const int m0 = bid * 64 + wave * 16;
    const int lrow = lane & 15;
    const int lk = lane >> 4;
    int arow = m0 + lrow;
    if (arow >= M) arow = M - 1;  // clamp; garbage rows never stored

    f32x4 acc[NT];
#pragma unroll
    for (int t = 0; t < NT; ++t) acc[t] = (f32x4){0.f, 0.f, 0.f, 0.f};

#pragma unroll
    for (int k0 = 0; k0 < 4; ++k0) {
        const int kb = k0 * 32 + lk * 8;
        short8 afrag;
        if (IN_BF16) {
            const unsigned short* A = (const unsigned short*)Ap;
            u32x4 v = __builtin_nontemporal_load((const u32x4*)&A[(size_t)arow * 128 + kb]);
#pragma unroll
            for (int q = 0; q < 4; ++q) {
                float lo = __uint_as_float(v[q] << 16);
                float hi = __uint_as_float(v[q] & 0xffff0000u);
                if (BIAS_RELU) {
                    lo = fmaxf(lo + bias[kb + 2 * q], 0.f);
                    hi = fmaxf(hi + bias[kb + 2 * q + 1], 0.f);
                }
                afrag[2 * q] = (short)f2bf(lo);
                afrag[2 * q + 1] = (short)f2bf(hi);
            }
        } else {
            const float* A = (const float*)Ap;
            const float* ap = &A[(size_t)arow * 128 + kb];
            f32x4 v0 = __builtin_nontemporal_load((const f32x4*)ap);
            f32x4 v1 = __builtin_nontemporal_load((const f32x4*)(ap + 4));
#pragma unroll
            for (int q = 0; q < 4; ++q) {
                afrag[q] = (short)f2bf(v0[q]);
                afrag[4 + q] = (short)f2bf(v1[q]);
            }
        }
#pragma unroll
        for (int t = 0; t < NT; ++t) {
            const int bcol = t * 16 + lrow;
            short8 bfrag = *(const short8*)&Wt[(size_t)bcol * 128 + kb];
            acc[t] = __builtin_amdgcn_mfma_f32_16x16x32_bf16(afrag, bfrag, acc[t], 0, 0, 0);
        }
    }

#pragma unroll
    for (int i = 0; i < 4; ++i) {
        int row = m0 + lk * 4 + i;
        if (row < M) {
#pragma unroll
            for (int t = 0; t < NT; ++t)
                out[(size_t)row * (NT * 16) + t * 16 + lrow] = f2bf(acc[t][i]);
        }
    }
}

__global__ __launch_bounds__(256) void k_gemm1(const float* __restrict__ x,
                                               const unsigned short* __restrict__ Wt1,
                                               unsigned short* __restrict__ hs1, int M) {
    gemm_body<8, false, false>(blockIdx.x, x, Wt1, nullptr, hs1, M);
}

__global__ __launch_bounds__(256) void k_gemm2(const unsigned short* __restrict__ agg1,
                                               const unsigned short* __restrict__ Wt2,
                                               const float* __restrict__ b1,
                                               unsigned short* __restrict__ hs2, int M) {
    gemm_body<4, true, true>(blockIdx.x, agg1, Wt2, b1, hs2, M);
}

__device__ __forceinline__ void acc8s(float a[8], u32x4 u, float d) {
    a[0] = fmaf(__uint_as_float(u[0] << 16), d, a[0]);
    a[1] = fmaf(__uint_as_float(u[0] & 0xffff0000u), d, a[1]);
    a[2] = fmaf(__uint_as_float(u[1] << 16), d, a[2]);
    a[3] = fmaf(__uint_as_float(u[1] & 0xffff0000u), d, a[3]);
    a[4] = fmaf(__uint_as_float(u[2] << 16), d, a[4]);
    a[5] = fmaf(__uint_as_float(u[2] & 0xffff0000u), d, a[5]);
    a[6] = fmaf(__uint_as_float(u[3] << 16), d, a[6]);
    a[7] = fmaf(__uint_as_float(u[3] & 0xffff0000u), d, a[7]);
}

// ---- CSR gather: res[v,:] = dis[v]*( dis[v]*hs[v,:] + sum_r dis[r]*hs[r,:] ) (+bias)
template <int D, bool OUT_F32, bool ADD_BIAS>
__global__ __launch_bounds__(256) void k_gather_csr(const unsigned short* __restrict__ hs,
                                                    const unsigned* __restrict__ csr,
                                                    const unsigned* __restrict__ off,
                                                    const float* __restrict__ dis,
                                                    const float* __restrict__ bias,
                                                    void* __restrict__ outp, int n) {
    const int TPN = D / 8;
    const int NPB = 256 / TPN;
    int v = blockIdx.x * NPB + (int)(threadIdx.x / TPN);
    int c = threadIdx.x % TPN;
    if (v >= n) return;
    const u32x4* h4 = (const u32x4*)hs;
    const size_t rs = D / 8;
    size_t base = (size_t)v * rs + c;

    unsigned s = off[v], e = off[v + 1];
    float dv = dis[v];

    float a[8];
#pragma unroll
    for (int j = 0; j < 8; ++j) a[j] = 0.f;
    acc8s(a, h4[base], dv);  // self-loop

    unsigned i = s;
    for (; i + 4 <= e; i += 4) {
        unsigned r0 = csr[i], r1 = csr[i + 1], r2 = csr[i + 2], r3 = csr[i + 3];
        float d0 = dis[r0], d1 = dis[r1], d2 = dis[r2], d3 = dis[r3];
        u32x4 m0 = h4[(size_t)r0 * rs + c];
        u32x4 m1 = h4[(size_t)r1 * rs + c];
        u32x4 m2 = h4[(size_t)r2 * rs + c];
        u32x4 m3 = h4[(size_t)r3 * rs + c];
        acc8s(a, m0, d0); acc8s(a, m1, d1); acc8s(a, m2, d2); acc8s(a, m3, d3);
    }
    for (; i < e; ++i) {
        unsigned r = csr[i];
        acc8s(a, h4[(size_t)r * rs + c], dis[r]);
    }

    if (OUT_F32) {
        float* o = (float*)outp;
        float rr[8];
#pragma unroll
        for (int j = 0; j < 8; ++j) {
            rr[j] = a[j] * dv;
            if (ADD_BIAS) rr[j] += bias[c * 8 + j];
        }
        f32x4 lov = {rr[0], rr[1], rr[2], rr[3]};
        f32x4 hiv = {rr[4], rr[5], rr[6], rr[7]};
        __builtin_nontemporal_store(lov, (f32x4*)&o[(size_t)v * D + c * 8]);
        __builtin_nontemporal_store(hiv, (f32x4*)&o[(size_t)v * D + c * 8 + 4]);
    } else {
        u32x4 o;
        o[0] = (unsigned)f2bf(a[0] * dv) | ((unsigned)f2bf(a[1] * dv) << 16);
        o[1] = (unsigned)f2bf(a[2] * dv) | ((unsigned)f2bf(a[3] * dv) << 16);
        o[2] = (unsigned)f2bf(a[4] * dv) | ((unsigned)f2bf(a[5] * dv) << 16);
        o[3] = (unsigned)f2bf(a[6] * dv) | ((unsigned)f2bf(a[7] * dv) << 16);
        ((u32x4*)outp)[base] = o;  // cached store: gemm2 re-reads agg1
    }
}

extern "C" void kernel_launch(void* const* d_in, const int* in_sizes, int n_in,
                              void* d_out, int out_size, void* d_ws, size_t ws_size,
                              hipStream_t stream) {
    const float* x  = (const float*)d_in[0];
    const int*   ei = (const int*)d_in[1];
    const float* W1 = (const float*)d_in[2];
    const float* b1 = (const float*)d_in[3];
    const float* W2 = (const float*)d_in[4];
    const float* b2 = (const float*)d_in[5];

    const int Din = 128;
    const int Nn = in_sizes[0] / Din;   // 50000
    const int E  = in_sizes[1] / 2;     // 800000
    const int* rowp = ei;
    const int* colp = ei + E;

    char* ws = (char*)d_ws;
    size_t off_ = 0;
    unsigned*       counts   = (unsigned*)(ws + off_);       off_ = alignup(off_ + (size_t)NB * NBLK_A * 4);
    unsigned*       bintot   = (unsigned*)(ws + off_);       off_ = alignup(off_ + NB * 4);
    unsigned*       edgebase = (unsigned*)(ws + off_);       off_ = alignup(off_ + (NB + 1) * 4);
    unsigned*       pairs    = (unsigned*)(ws + off_);       off_ = alignup(off_ + (size_t)E * 4);
    unsigned*       csr      = (unsigned*)(ws + off_);       off_ = alignup(off_ + (size_t)E * 4);
    unsigned*       offv     = (unsigned*)(ws + off_);       off_ = alignup(off_ + (size_t)(Nn + 1) * 4);
    float*          dis      = (float*)(ws + off_);          off_ = alignup(off_ + (size_t)Nn * 4);
    unsigned short* Wt1      = (unsigned short*)(ws + off_); off_ = alignup(off_ + 128 * 128 * 2);
    unsigned short* Wt2      = (unsigned short*)(ws + off_); off_ = alignup(off_ + 128 * 64 * 2);
    unsigned short* hs1      = (unsigned short*)(ws + off_); off_ = alignup(off_ + (size_t)Nn * 128 * 2);
    unsigned short* agg1     = (unsigned short*)(ws + off_); off_ = alignup(off_ + (size_t)Nn * 128 * 2);
    unsigned short* hs2      = hs1;  // hs1 dead after gather1; reuse
    float*          outp     = (float*)d_out;

    // graph build: histogram -> scans -> scatter pairs -> per-bin CSR build
    k_hist<<<NBLK_A + 64, 256, 0, stream>>>(colp, E, counts, W1, W2, Wt1, Wt2);
    k_scanA<<<NB, 256, 0, stream>>>(counts, bintot);
    k_scanB<<<1, 256, 0, stream>>>(bintot, edgebase, E);
    k_scatter<<<NBLK_A, 256, 0, stream>>>(colp, rowp, E, counts, edgebase, pairs);
    k_binbuild<<<NB, 256, 0, stream>>>(pairs, edgebase, csr, offv, dis, Nn);

    // layer 1: hs1 = bf16(x @ W1)
    k_gemm1<<<(Nn + 63) / 64, 256, 0, stream>>>(x, Wt1, hs1, Nn);

    // agg1 = bf16( dis[v] * (dis[v]*hs1[v] + sum dis[r]*hs1[r]) )
    k_gather_csr<128, false, false><<<(Nn + 15) / 16, 256, 0, stream>>>(
        hs1, csr, offv, dis, nullptr, agg1, Nn);

    // layer 2: hs2 = bf16( relu(agg1 + b1) @ W2 )
    k_gemm2<<<(Nn + 63) / 64, 256, 0, stream>>>(agg1, Wt2, b1, hs2, Nn);

    // out = dis[v] * (dis[v]*hs2[v] + sum dis[r]*hs2[r]) + b2   (fp32)
    k_gather_csr<64, true, true><<<(Nn + 31) / 32, 256, 0, stream>>>(
        hs2, csr, offv, dis, b2, (void*)outp, Nn);
}